// Round 1
// baseline (5004.121 us; speedup 1.0000x reference)
//
#include <hip/hip_runtime.h>
#include <math.h>

#define NN 100000
#define EE 1600000
#define ET (EE + NN)   // 1,700,000 edges incl self-loops
#define FIN 128
#define D1 64          // H1*C1
#define H1 8
#define C1 8
#define C2 40
#define NEG 0.2f
#define EPSV 1e-16f

// ---------- helpers ----------

__device__ __forceinline__ void atomicMaxF(float* addr, float val) {
  // classic two-case float atomic max; works with -inf init (0xFF800000)
  if (val >= 0.f)
    atomicMax((int*)addr, __float_as_int(val));
  else
    atomicMin((unsigned int*)addr, __float_as_uint(val));
}

__global__ void fill_f32(float* __restrict__ p, float v, int n) {
  int i = blockIdx.x * blockDim.x + threadIdx.x;
  if (i < n) p[i] = v;
}

// ---------- layer 1: h1 = x @ W1  (+ per-head attention dots) ----------
// block = 256 threads = 4 waves, one wave (64 lanes) per node, lane = out col.
__global__ __launch_bounds__(256) void gemm1_kernel(
    const float* __restrict__ x, const float* __restrict__ W,
    const float* __restrict__ att_s, const float* __restrict__ att_d,
    float* __restrict__ h, float* __restrict__ as, float* __restrict__ ad) {
  __shared__ float sW[FIN * D1];   // 32 KB
  __shared__ float sx[4 * FIN];    // 2 KB
  int t = threadIdx.x;
  for (int i = t; i < FIN * D1; i += 256) sW[i] = W[i];
  int node0 = blockIdx.x * 4;
  for (int i = t; i < 4 * FIN; i += 256) {
    int n = node0 + (i >> 7);
    sx[i] = (n < NN) ? x[(long)n * FIN + (i & 127)] : 0.f;
  }
  __syncthreads();
  int ln = t >> 6, col = t & 63;
  int n = node0 + ln;
  float acc = 0.f;
  const float* xr = &sx[ln * FIN];
#pragma unroll 8
  for (int k = 0; k < FIN; ++k) acc = fmaf(xr[k], sW[k * D1 + col], acc);
  // per-head dots: head = col>>3, channel = col&7 (att arrays are [H1,C1] flat)
  float vs = acc * att_s[col];
  float vd = acc * att_d[col];
#pragma unroll
  for (int off = 1; off < 8; off <<= 1) {
    vs += __shfl_xor(vs, off, 64);
    vd += __shfl_xor(vd, off, 64);
  }
  if (n < NN) {
    h[(long)n * D1 + col] = acc;
    if ((col & 7) == 0) {
      as[n * H1 + (col >> 3)] = vs;
      ad[n * H1 + (col >> 3)] = vd;
    }
  }
}

// ---------- edge passes, layer 1 (H=8) ----------
__device__ __forceinline__ void edge_sd(int e, const int* __restrict__ ei, int& s, int& d) {
  if (e < EE) { s = ei[e]; d = ei[EE + e]; }
  else        { s = e - EE; d = s; }
}

__global__ void edge_max1(const int* __restrict__ ei, const float* __restrict__ as,
                          const float* __restrict__ ad, float* __restrict__ emax) {
  int gid = blockIdx.x * 256 + threadIdx.x;
  if (gid >= ET * H1) return;
  int e = gid >> 3, hh = gid & 7;
  int s, d; edge_sd(e, ei, s, d);
  float v = as[s * H1 + hh] + ad[d * H1 + hh];
  v = v >= 0.f ? v : NEG * v;
  atomicMaxF(&emax[d * H1 + hh], v);
}

__global__ void edge_sum1(const int* __restrict__ ei, const float* __restrict__ as,
                          const float* __restrict__ ad, const float* __restrict__ emax,
                          float* __restrict__ den) {
  int gid = blockIdx.x * 256 + threadIdx.x;
  if (gid >= ET * H1) return;
  int e = gid >> 3, hh = gid & 7;
  int s, d; edge_sd(e, ei, s, d);
  int di = d * H1 + hh;
  float v = as[s * H1 + hh] + ad[di];
  v = v >= 0.f ? v : NEG * v;
  atomicAdd(&den[di], __expf(v - emax[di]));
}

__global__ void edge_scat1(const int* __restrict__ ei, const float* __restrict__ as,
                           const float* __restrict__ ad, const float* __restrict__ emax,
                           const float* __restrict__ den, const float* __restrict__ h,
                           float* __restrict__ acc) {
  int gid = blockIdx.x * 256 + threadIdx.x;
  if (gid >= ET * H1) return;
  int e = gid >> 3, hh = gid & 7;
  int s, d; edge_sd(e, ei, s, d);
  int di = d * H1 + hh;
  float v = as[s * H1 + hh] + ad[di];
  v = v >= 0.f ? v : NEG * v;
  float alpha = __expf(v - emax[di]) / (den[di] + EPSV);
  const float4* hp = (const float4*)(h + (long)s * D1 + hh * C1);
  float4 p0 = hp[0], p1 = hp[1];
  float* o = acc + (long)d * D1 + hh * C1;
  atomicAdd(o + 0, p0.x * alpha); atomicAdd(o + 1, p0.y * alpha);
  atomicAdd(o + 2, p0.z * alpha); atomicAdd(o + 3, p0.w * alpha);
  atomicAdd(o + 4, p1.x * alpha); atomicAdd(o + 5, p1.y * alpha);
  atomicAdd(o + 6, p1.z * alpha); atomicAdd(o + 7, p1.w * alpha);
}

// emb = elu(acc + b1), in place on the emb output region
__global__ void elu_bias(float* __restrict__ emb, const float* __restrict__ b) {
  int i = blockIdx.x * 256 + threadIdx.x;
  if (i >= NN * D1) return;
  float v = emb[i] + b[i & (D1 - 1)];
  emb[i] = v > 0.f ? v : expm1f(v);
}

// ---------- layer 2: h2 = emb @ W2 ----------
__global__ __launch_bounds__(256) void gemm2_kernel(
    const float* __restrict__ emb, const float* __restrict__ W2, float* __restrict__ h2) {
  __shared__ float sW[D1 * C2];  // 10 KB
  int t = threadIdx.x;
  for (int i = t; i < D1 * C2; i += 256) sW[i] = W2[i];
  __syncthreads();
  int gid = blockIdx.x * 256 + t;
  if (gid >= NN * C2) return;
  int n = gid / C2, c = gid % C2;
  float accv = 0.f;
  const float* er = &emb[(long)n * D1];
#pragma unroll 8
  for (int k = 0; k < D1; ++k) accv = fmaf(er[k], sW[k * C2 + c], accv);
  h2[gid] = accv;
}

__global__ void attdot2_kernel(const float* __restrict__ h2, const float* __restrict__ att_s,
                               const float* __restrict__ att_d,
                               float* __restrict__ as, float* __restrict__ ad) {
  int n = blockIdx.x * blockDim.x + threadIdx.x;
  if (n >= NN) return;
  float vs = 0.f, vd = 0.f;
  const float* r = &h2[(long)n * C2];
#pragma unroll
  for (int c = 0; c < C2; ++c) {
    float v = r[c];
    vs = fmaf(v, att_s[c], vs);
    vd = fmaf(v, att_d[c], vd);
  }
  as[n] = vs;
  ad[n] = vd;
}

// ---------- edge passes, layer 2 (H=1, C=40) ----------
__global__ void edge_max2(const int* __restrict__ ei, const float* __restrict__ as,
                          const float* __restrict__ ad, float* __restrict__ emax) {
  int e = blockIdx.x * 256 + threadIdx.x;
  if (e >= ET) return;
  int s, d; edge_sd(e, ei, s, d);
  float v = as[s] + ad[d];
  v = v >= 0.f ? v : NEG * v;
  atomicMaxF(&emax[d], v);
}

__global__ void edge_sum2(const int* __restrict__ ei, const float* __restrict__ as,
                          const float* __restrict__ ad, const float* __restrict__ emax,
                          float* __restrict__ den) {
  int e = blockIdx.x * 256 + threadIdx.x;
  if (e >= ET) return;
  int s, d; edge_sd(e, ei, s, d);
  float v = as[s] + ad[d];
  v = v >= 0.f ? v : NEG * v;
  atomicAdd(&den[d], __expf(v - emax[d]));
}

// 8 threads per edge, 5 channels each
__global__ void edge_scat2(const int* __restrict__ ei, const float* __restrict__ as,
                           const float* __restrict__ ad, const float* __restrict__ emax,
                           const float* __restrict__ den, const float* __restrict__ h2,
                           float* __restrict__ acc) {
  int gid = blockIdx.x * 256 + threadIdx.x;
  if (gid >= ET * 8) return;
  int e = gid >> 3, part = gid & 7;
  int s, d; edge_sd(e, ei, s, d);
  float v = as[s] + ad[d];
  v = v >= 0.f ? v : NEG * v;
  float alpha = __expf(v - emax[d]) / (den[d] + EPSV);
  int c0 = part * 5;
  const float* hp = h2 + (long)s * C2 + c0;
  float* o = acc + (long)d * C2 + c0;
#pragma unroll
  for (int j = 0; j < 5; ++j) atomicAdd(o + j, hp[j] * alpha);
}

// log_softmax over 40 classes, one thread per node; adds b2 here
__global__ void logsoftmax_kernel(const float* __restrict__ logits, const float* __restrict__ b2,
                                  float* __restrict__ out) {
  int n = blockIdx.x * blockDim.x + threadIdx.x;
  if (n >= NN) return;
  float vals[C2];
  float m = -INFINITY;
#pragma unroll
  for (int c = 0; c < C2; ++c) {
    float v = logits[(long)n * C2 + c] + b2[c];
    vals[c] = v;
    m = fmaxf(m, v);
  }
  float sum = 0.f;
#pragma unroll
  for (int c = 0; c < C2; ++c) sum += __expf(vals[c] - m);
  float ls = logf(sum);
#pragma unroll
  for (int c = 0; c < C2; ++c) out[(long)n * C2 + c] = vals[c] - m - ls;
}

// ---------- launch ----------
extern "C" void kernel_launch(void* const* d_in, const int* in_sizes, int n_in,
                              void* d_out, int out_size, void* d_ws, size_t ws_size,
                              hipStream_t stream) {
  const float* x    = (const float*)d_in[0];
  const float* W1   = (const float*)d_in[1];
  const float* as1w = (const float*)d_in[2];
  const float* ad1w = (const float*)d_in[3];
  const float* b1   = (const float*)d_in[4];
  const float* W2   = (const float*)d_in[5];
  const float* as2w = (const float*)d_in[6];
  const float* ad2w = (const float*)d_in[7];
  const float* b2   = (const float*)d_in[8];
  const int*   ei   = (const int*)d_in[9];

  float* out   = (float*)d_out;
  float* outls = out;                    // [N,40] log_softmax
  float* emb   = out + (long)NN * C2;    // [N,64] emb (also layer-1 accumulator)

  float* ws = (float*)d_ws;
  float* h1    = ws; ws += (long)NN * D1;
  float* asrc1 = ws; ws += (long)NN * H1;
  float* adst1 = ws; ws += (long)NN * H1;
  float* emax1 = ws; ws += (long)NN * H1;
  float* den1  = ws; ws += (long)NN * H1;
  float* h2    = ws; ws += (long)NN * C2;
  float* asrc2 = ws; ws += NN;
  float* adst2 = ws; ws += NN;
  float* emax2 = ws; ws += NN;
  float* den2  = ws; ws += NN;
  float* logits= ws; ws += (long)NN * C2;

  // init accumulators
  hipMemsetAsync(emb, 0, sizeof(float) * (size_t)NN * D1, stream);
  hipMemsetAsync(den1, 0, sizeof(float) * (size_t)NN * H1, stream);
  hipMemsetAsync(logits, 0, sizeof(float) * (size_t)NN * C2, stream);
  hipMemsetAsync(den2, 0, sizeof(float) * (size_t)NN, stream);
  fill_f32<<<(NN * H1 + 255) / 256, 256, 0, stream>>>(emax1, -INFINITY, NN * H1);
  fill_f32<<<(NN + 255) / 256, 256, 0, stream>>>(emax2, -INFINITY, NN);

  // layer 1
  gemm1_kernel<<<(NN + 3) / 4, 256, 0, stream>>>(x, W1, as1w, ad1w, h1, asrc1, adst1);
  int nbE8 = (ET * H1 + 255) / 256;  // 13.6M threads
  edge_max1<<<nbE8, 256, 0, stream>>>(ei, asrc1, adst1, emax1);
  edge_sum1<<<nbE8, 256, 0, stream>>>(ei, asrc1, adst1, emax1, den1);
  edge_scat1<<<nbE8, 256, 0, stream>>>(ei, asrc1, adst1, emax1, den1, h1, emb);
  elu_bias<<<(NN * D1 + 255) / 256, 256, 0, stream>>>(emb, b1);

  // layer 2
  gemm2_kernel<<<(NN * C2 + 255) / 256, 256, 0, stream>>>(emb, W2, h2);
  attdot2_kernel<<<(NN + 255) / 256, 256, 0, stream>>>(h2, as2w, ad2w, asrc2, adst2);
  int nbE1 = (ET + 255) / 256;
  edge_max2<<<nbE1, 256, 0, stream>>>(ei, asrc2, adst2, emax2);
  edge_sum2<<<nbE1, 256, 0, stream>>>(ei, asrc2, adst2, emax2, den2);
  edge_scat2<<<nbE8, 256, 0, stream>>>(ei, asrc2, adst2, emax2, den2, h2, logits);
  logsoftmax_kernel<<<(NN + 255) / 256, 256, 0, stream>>>(logits, b2, outls);
}

// Round 2
// 831.546 us; speedup vs baseline: 6.0179x; 6.0179x over previous
//
#include <hip/hip_runtime.h>
#include <math.h>

#define NN 100000
#define EE 1600000
#define ET (EE + NN)   // 1,700,000 edges incl self-loops
#define FIN 128
#define D1 64          // H1*C1
#define H1 8
#define C1 8
#define C2 40
#define NEG 0.2f
#define EPSV 1e-16f

__device__ __forceinline__ void edge_sd(int e, const int* __restrict__ ei, int& s, int& d) {
  if (e < EE) { s = ei[e]; d = ei[EE + e]; }
  else        { s = e - EE; d = s; }
}

// ---------- CSR build ----------
__global__ void deg_kernel(const int* __restrict__ ei, int* __restrict__ deg) {
  int e = blockIdx.x * 256 + threadIdx.x;
  if (e >= ET) return;
  int s, d; edge_sd(e, ei, s, d);
  atomicAdd(&deg[d], 1);
}

// block scans 1024 elements (256 thr x 4)
#define NB_SCAN ((NN + 1023) / 1024)
__global__ __launch_bounds__(256) void scan1_kernel(const int* __restrict__ deg,
                                                    int* __restrict__ rowptr,
                                                    int* __restrict__ partial) {
  __shared__ int sd[256];
  int b = blockIdx.x, t = threadIdx.x;
  int base = b * 1024 + t * 4;
  int v[4], s = 0;
#pragma unroll
  for (int j = 0; j < 4; ++j) { int idx = base + j; v[j] = (idx < NN) ? deg[idx] : 0; s += v[j]; }
  sd[t] = s;
  __syncthreads();
  for (int off = 1; off < 256; off <<= 1) {
    int x = sd[t];
    int y = (t >= off) ? sd[t - off] : 0;
    __syncthreads();
    sd[t] = x + y;
    __syncthreads();
  }
  int run = sd[t] - s;  // exclusive base for this thread
#pragma unroll
  for (int j = 0; j < 4; ++j) {
    int idx = base + j;
    if (idx < NN) rowptr[idx] = run;
    run += v[j];
  }
  if (t == 255) partial[b] = sd[255];
}

__global__ void scan2_kernel(int* __restrict__ partial) {
  if (threadIdx.x == 0 && blockIdx.x == 0) {
    int run = 0;
    for (int i = 0; i < NB_SCAN; ++i) { int p = partial[i]; partial[i] = run; run += p; }
  }
}

__global__ void scan3_kernel(int* __restrict__ rowptr, const int* __restrict__ partial) {
  int idx = blockIdx.x * 256 + threadIdx.x;
  if (idx < NN) rowptr[idx] += partial[idx >> 10];
}

__global__ void fill_csr_kernel(const int* __restrict__ ei, const int* __restrict__ rowptr,
                                int* __restrict__ cursor, int* __restrict__ csr) {
  int e = blockIdx.x * 256 + threadIdx.x;
  if (e >= ET) return;
  int s, d; edge_sd(e, ei, s, d);
  int pos = atomicAdd(&cursor[d], 1);
  csr[rowptr[d] + pos] = s;
}

// ---------- layer 1: h1 = x @ W1  (+ per-head attention dots) ----------
__global__ __launch_bounds__(256) void gemm1_kernel(
    const float* __restrict__ x, const float* __restrict__ W,
    const float* __restrict__ att_s, const float* __restrict__ att_d,
    float* __restrict__ h, float* __restrict__ as, float* __restrict__ ad) {
  __shared__ float sW[FIN * D1];   // 32 KB
  __shared__ float sx[4 * FIN];    // 2 KB
  int t = threadIdx.x;
  for (int i = t; i < FIN * D1; i += 256) sW[i] = W[i];
  int node0 = blockIdx.x * 4;
  for (int i = t; i < 4 * FIN; i += 256) {
    int n = node0 + (i >> 7);
    sx[i] = (n < NN) ? x[(long)n * FIN + (i & 127)] : 0.f;
  }
  __syncthreads();
  int ln = t >> 6, col = t & 63;
  int n = node0 + ln;
  float acc = 0.f;
  const float* xr = &sx[ln * FIN];
#pragma unroll 8
  for (int k = 0; k < FIN; ++k) acc = fmaf(xr[k], sW[k * D1 + col], acc);
  float vs = acc * att_s[col];
  float vd = acc * att_d[col];
#pragma unroll
  for (int off = 1; off < 8; off <<= 1) {
    vs += __shfl_xor(vs, off, 64);
    vd += __shfl_xor(vd, off, 64);
  }
  if (n < NN) {
    h[(long)n * D1 + col] = acc;
    if ((col & 7) == 0) {
      as[n * H1 + (col >> 3)] = vs;
      ad[n * H1 + (col >> 3)] = vd;
    }
  }
}

// ---------- fused aggregation, layer 1: softmax + gather + ELU + bias ----------
// one wave per dst node; lane = output column (head = lane>>3)
__global__ __launch_bounds__(256) void agg1_kernel(
    const int* __restrict__ rowptr, const int* __restrict__ csr,
    const float* __restrict__ as, const float* __restrict__ ad,
    const float* __restrict__ h, const float* __restrict__ b1,
    float* __restrict__ emb) {
  int node = blockIdx.x * 4 + (threadIdx.x >> 6);
  if (node >= NN) return;
  int lane = threadIdx.x & 63;
  int beg = rowptr[node];
  int end = (node == NN - 1) ? ET : rowptr[node + 1];

  // phase 1: per-head max and denom. lane = slot*8 + head
  int hh = lane & 7, slot = lane >> 3;
  float adv = ad[node * H1 + hh];
  float m = -INFINITY;
  for (int i = beg + slot; i < end; i += 8) {
    int s = csr[i];
    float v = as[s * H1 + hh] + adv;
    v = v >= 0.f ? v : NEG * v;
    m = fmaxf(m, v);
  }
  m = fmaxf(m, __shfl_xor(m, 8, 64));
  m = fmaxf(m, __shfl_xor(m, 16, 64));
  m = fmaxf(m, __shfl_xor(m, 32, 64));
  float den = 0.f;
  for (int i = beg + slot; i < end; i += 8) {
    int s = csr[i];
    float v = as[s * H1 + hh] + adv;
    v = v >= 0.f ? v : NEG * v;
    den += __expf(v - m);
  }
  den += __shfl_xor(den, 8, 64);
  den += __shfl_xor(den, 16, 64);
  den += __shfl_xor(den, 32, 64);

  // phase 2: weighted gather. my output head = lane>>3
  int myh = lane >> 3;
  float maxh = __shfl(m, myh, 64);
  float invd = 1.f / (__shfl(den, myh, 64) + EPSV);
  float adv2 = ad[node * H1 + myh];
  float acc = 0.f;
  for (int i = beg; i < end; ++i) {
    int s = csr[i];
    float v = as[s * H1 + myh] + adv2;
    v = v >= 0.f ? v : NEG * v;
    float alpha = __expf(v - maxh) * invd;
    acc = fmaf(h[(long)s * D1 + lane], alpha, acc);
  }
  float o = acc + b1[lane];
  emb[(long)node * D1 + lane] = o > 0.f ? o : expm1f(o);
}

// ---------- layer 2: h2 = emb @ W2 ----------
__global__ __launch_bounds__(256) void gemm2_kernel(
    const float* __restrict__ emb, const float* __restrict__ W2, float* __restrict__ h2) {
  __shared__ float sW[D1 * C2];  // 10 KB
  int t = threadIdx.x;
  for (int i = t; i < D1 * C2; i += 256) sW[i] = W2[i];
  __syncthreads();
  int gid = blockIdx.x * 256 + t;
  if (gid >= NN * C2) return;
  int n = gid / C2, c = gid % C2;
  float accv = 0.f;
  const float* er = &emb[(long)n * D1];
#pragma unroll 8
  for (int k = 0; k < D1; ++k) accv = fmaf(er[k], sW[k * C2 + c], accv);
  h2[gid] = accv;
}

__global__ void attdot2_kernel(const float* __restrict__ h2, const float* __restrict__ att_s,
                               const float* __restrict__ att_d,
                               float* __restrict__ as, float* __restrict__ ad) {
  int n = blockIdx.x * blockDim.x + threadIdx.x;
  if (n >= NN) return;
  float vs = 0.f, vd = 0.f;
  const float* r = &h2[(long)n * C2];
#pragma unroll
  for (int c = 0; c < C2; ++c) {
    float v = r[c];
    vs = fmaf(v, att_s[c], vs);
    vd = fmaf(v, att_d[c], vd);
  }
  as[n] = vs;
  ad[n] = vd;
}

// ---------- fused aggregation, layer 2 + bias + log_softmax ----------
// one wave per dst node; lanes 0..39 = class columns
__global__ __launch_bounds__(256) void agg2_kernel(
    const int* __restrict__ rowptr, const int* __restrict__ csr,
    const float* __restrict__ as, const float* __restrict__ ad,
    const float* __restrict__ h2, const float* __restrict__ b2,
    float* __restrict__ out) {
  int node = blockIdx.x * 4 + (threadIdx.x >> 6);
  if (node >= NN) return;
  int lane = threadIdx.x & 63;
  int beg = rowptr[node];
  int end = (node == NN - 1) ? ET : rowptr[node + 1];
  float adv = ad[node];

  // phase 1: max and denom over all in-edges (each lane strides by 64)
  float m = -INFINITY;
  for (int i = beg + lane; i < end; i += 64) {
    float v = as[csr[i]] + adv;
    v = v >= 0.f ? v : NEG * v;
    m = fmaxf(m, v);
  }
#pragma unroll
  for (int off = 1; off < 64; off <<= 1) m = fmaxf(m, __shfl_xor(m, off, 64));
  float den = 0.f;
  for (int i = beg + lane; i < end; i += 64) {
    float v = as[csr[i]] + adv;
    v = v >= 0.f ? v : NEG * v;
    den += __expf(v - m);
  }
#pragma unroll
  for (int off = 1; off < 64; off <<= 1) den += __shfl_xor(den, off, 64);
  float invd = 1.f / (den + EPSV);

  // phase 2: weighted gather of h2 rows (lanes 0..39 active on the load)
  float acc = 0.f;
  for (int i = beg; i < end; ++i) {
    int s = csr[i];
    float v = as[s] + adv;
    v = v >= 0.f ? v : NEG * v;
    float alpha = __expf(v - m) * invd;
    if (lane < C2) acc = fmaf(h2[(long)s * C2 + lane], alpha, acc);
  }

  // fused bias + log_softmax over 40 classes
  float val = (lane < C2) ? acc + b2[lane] : -INFINITY;
  float m2 = val;
#pragma unroll
  for (int off = 1; off < 64; off <<= 1) m2 = fmaxf(m2, __shfl_xor(m2, off, 64));
  float ex = (lane < C2) ? __expf(val - m2) : 0.f;
  float sum = ex;
#pragma unroll
  for (int off = 1; off < 64; off <<= 1) sum += __shfl_xor(sum, off, 64);
  if (lane < C2) out[(long)node * C2 + lane] = val - m2 - logf(sum);
}

// ---------- launch ----------
extern "C" void kernel_launch(void* const* d_in, const int* in_sizes, int n_in,
                              void* d_out, int out_size, void* d_ws, size_t ws_size,
                              hipStream_t stream) {
  const float* x    = (const float*)d_in[0];
  const float* W1   = (const float*)d_in[1];
  const float* as1w = (const float*)d_in[2];
  const float* ad1w = (const float*)d_in[3];
  const float* b1   = (const float*)d_in[4];
  const float* W2   = (const float*)d_in[5];
  const float* as2w = (const float*)d_in[6];
  const float* ad2w = (const float*)d_in[7];
  const float* b2   = (const float*)d_in[8];
  const int*   ei   = (const int*)d_in[9];

  float* out   = (float*)d_out;
  float* outls = out;                    // [N,40] log_softmax
  float* emb   = out + (long)NN * C2;    // [N,64] emb

  char* wsb = (char*)d_ws;
  float* h1    = (float*)wsb; wsb += sizeof(float) * (size_t)NN * D1;
  float* asrc1 = (float*)wsb; wsb += sizeof(float) * (size_t)NN * H1;
  float* adst1 = (float*)wsb; wsb += sizeof(float) * (size_t)NN * H1;
  float* h2    = (float*)wsb; wsb += sizeof(float) * (size_t)NN * C2;
  float* asrc2 = (float*)wsb; wsb += sizeof(float) * (size_t)NN;
  float* adst2 = (float*)wsb; wsb += sizeof(float) * (size_t)NN;
  int* deg     = (int*)wsb;   wsb += sizeof(int) * (size_t)NN;
  int* rowptr  = (int*)wsb;   wsb += sizeof(int) * (size_t)NN;
  int* cursor  = (int*)wsb;   wsb += sizeof(int) * (size_t)NN;
  int* partial = (int*)wsb;   wsb += sizeof(int) * 256;
  int* csr     = (int*)wsb;   wsb += sizeof(int) * (size_t)ET;

  // CSR build (per call; ws is re-poisoned each launch)
  hipMemsetAsync(deg, 0, sizeof(int) * (size_t)NN, stream);
  hipMemsetAsync(cursor, 0, sizeof(int) * (size_t)NN, stream);
  int nbE = (ET + 255) / 256;
  deg_kernel<<<nbE, 256, 0, stream>>>(ei, deg);
  scan1_kernel<<<NB_SCAN, 256, 0, stream>>>(deg, rowptr, partial);
  scan2_kernel<<<1, 64, 0, stream>>>(partial);
  scan3_kernel<<<(NN + 255) / 256, 256, 0, stream>>>(rowptr, partial);
  fill_csr_kernel<<<nbE, 256, 0, stream>>>(ei, rowptr, cursor, csr);

  // layer 1
  gemm1_kernel<<<(NN + 3) / 4, 256, 0, stream>>>(x, W1, as1w, ad1w, h1, asrc1, adst1);
  agg1_kernel<<<(NN + 3) / 4, 256, 0, stream>>>(rowptr, csr, asrc1, adst1, h1, b1, emb);

  // layer 2
  gemm2_kernel<<<(NN * C2 + 255) / 256, 256, 0, stream>>>(emb, W2, h2);
  attdot2_kernel<<<(NN + 255) / 256, 256, 0, stream>>>(h2, as2w, ad2w, asrc2, adst2);
  agg2_kernel<<<(NN + 3) / 4, 256, 0, stream>>>(rowptr, csr, asrc2, adst2, h2, b2, outls);
}

// Round 3
// 673.932 us; speedup vs baseline: 7.4253x; 1.2339x over previous
//
#include <hip/hip_runtime.h>
#include <hip/hip_fp16.h>
#include <math.h>

#define NN 100000
#define EE 1600000
#define ET (EE + NN)   // 1,700,000 edges incl self-loops
#define FIN 128
#define D1 64          // H1*C1
#define H1 8
#define C1 8
#define C2 40
#define NEG 0.2f
#define EPSV 1e-16f

__device__ __forceinline__ void edge_sd(int e, const int* __restrict__ ei, int& s, int& d) {
  if (e < EE) { s = ei[e]; d = ei[EE + e]; }
  else        { s = e - EE; d = s; }
}

// ---------- CSR build ----------
__global__ void deg_kernel(const int* __restrict__ ei, int* __restrict__ deg) {
  int e = blockIdx.x * 256 + threadIdx.x;
  if (e >= ET) return;
  int s, d; edge_sd(e, ei, s, d);
  atomicAdd(&deg[d], 1);
}

#define NB_SCAN ((NN + 1023) / 1024)
__global__ __launch_bounds__(256) void scan1_kernel(const int* __restrict__ deg,
                                                    int* __restrict__ rowptr,
                                                    int* __restrict__ partial) {
  __shared__ int sd[256];
  int b = blockIdx.x, t = threadIdx.x;
  int base = b * 1024 + t * 4;
  int v[4], s = 0;
#pragma unroll
  for (int j = 0; j < 4; ++j) { int idx = base + j; v[j] = (idx < NN) ? deg[idx] : 0; s += v[j]; }
  sd[t] = s;
  __syncthreads();
  for (int off = 1; off < 256; off <<= 1) {
    int x = sd[t];
    int y = (t >= off) ? sd[t - off] : 0;
    __syncthreads();
    sd[t] = x + y;
    __syncthreads();
  }
  int run = sd[t] - s;
#pragma unroll
  for (int j = 0; j < 4; ++j) {
    int idx = base + j;
    if (idx < NN) rowptr[idx] = run;
    run += v[j];
  }
  if (t == 255) partial[b] = sd[255];
}

__global__ void scan2_kernel(int* __restrict__ partial) {
  if (threadIdx.x == 0 && blockIdx.x == 0) {
    int run = 0;
    for (int i = 0; i < NB_SCAN; ++i) { int p = partial[i]; partial[i] = run; run += p; }
  }
}

__global__ void scan3_kernel(int* __restrict__ rowptr, const int* __restrict__ partial) {
  int idx = blockIdx.x * 256 + threadIdx.x;
  if (idx < NN) rowptr[idx] += partial[idx >> 10];
}

__global__ void fill_csr_kernel(const int* __restrict__ ei, const int* __restrict__ rowptr,
                                int* __restrict__ cursor, int* __restrict__ csr) {
  int e = blockIdx.x * 256 + threadIdx.x;
  if (e >= ET) return;
  int s, d; edge_sd(e, ei, s, d);
  int pos = atomicAdd(&cursor[d], 1);
  csr[rowptr[d] + pos] = s;
}

// ---------- layer 1: h1 = x @ W1 (fp16 out) + per-head attention dots ----------
__global__ __launch_bounds__(256) void gemm1_kernel(
    const float* __restrict__ x, const float* __restrict__ W,
    const float* __restrict__ att_s, const float* __restrict__ att_d,
    __half* __restrict__ h, float* __restrict__ as, float* __restrict__ ad) {
  __shared__ float sW[FIN * D1];   // 32 KB
  __shared__ float sx[4 * FIN];    // 2 KB
  int t = threadIdx.x;
  for (int i = t; i < FIN * D1; i += 256) sW[i] = W[i];
  int node0 = blockIdx.x * 4;
  for (int i = t; i < 4 * FIN; i += 256) {
    int n = node0 + (i >> 7);
    sx[i] = (n < NN) ? x[(long)n * FIN + (i & 127)] : 0.f;
  }
  __syncthreads();
  int ln = t >> 6, col = t & 63;
  int n = node0 + ln;
  float acc = 0.f;
  const float* xr = &sx[ln * FIN];
#pragma unroll 8
  for (int k = 0; k < FIN; ++k) acc = fmaf(xr[k], sW[k * D1 + col], acc);
  float vs = acc * att_s[col];
  float vd = acc * att_d[col];
#pragma unroll
  for (int off = 1; off < 8; off <<= 1) {
    vs += __shfl_xor(vs, off, 64);
    vd += __shfl_xor(vd, off, 64);
  }
  if (n < NN) {
    h[(long)n * D1 + col] = __float2half(acc);
    if ((col & 7) == 0) {
      as[n * H1 + (col >> 3)] = vs;
      ad[n * H1 + (col >> 3)] = vd;
    }
  }
}

// ---------- fused aggregation, layer 1 ----------
// one wave per dst node; lane = output column. alpha computed once per
// (edge, head) by lane = edge_local*8 + head, then shfl-broadcast.
__global__ __launch_bounds__(256) void agg1_kernel(
    const int* __restrict__ rowptr, const int* __restrict__ csr,
    const float* __restrict__ as, const float* __restrict__ ad,
    const __half* __restrict__ h, const float* __restrict__ b1,
    float* __restrict__ emb) {
  int node = blockIdx.x * 4 + (threadIdx.x >> 6);
  if (node >= NN) return;
  int lane = threadIdx.x & 63;
  int beg = rowptr[node];
  int end = (node == NN - 1) ? ET : rowptr[node + 1];
  int hh = lane & 7, el = lane >> 3;

  // phase 1: per-head max and denom (lane = el*8 + hh, el strides edges)
  float adv = ad[node * H1 + hh];
  float m = -INFINITY;
  for (int i = beg + el; i < end; i += 8) {
    float v = as[csr[i] * H1 + hh] + adv;
    v = v >= 0.f ? v : NEG * v;
    m = fmaxf(m, v);
  }
  m = fmaxf(m, __shfl_xor(m, 8, 64));
  m = fmaxf(m, __shfl_xor(m, 16, 64));
  m = fmaxf(m, __shfl_xor(m, 32, 64));
  float den = 0.f;
  for (int i = beg + el; i < end; i += 8) {
    float v = as[csr[i] * H1 + hh] + adv;
    v = v >= 0.f ? v : NEG * v;
    den += __expf(v - m);
  }
  den += __shfl_xor(den, 8, 64);
  den += __shfl_xor(den, 16, 64);
  den += __shfl_xor(den, 32, 64);
  float invd = 1.f / (den + EPSV);

  // phase 2: chunked weighted gather, 8 edges at a time
  int myh = lane >> 3;
  float acc = 0.f;
  int i = beg;
  for (; i + 8 <= end; i += 8) {
    int s8 = csr[i + el];                       // edge i+el (8 lanes share)
    float v = as[s8 * H1 + hh] + adv;           // alpha(edge el, head hh)
    v = v >= 0.f ? v : NEG * v;
    float al = __expf(v - m) * invd;
    float hv[8];
#pragma unroll
    for (int j = 0; j < 8; ++j) {
      int sj = __shfl(s8, j * 8, 64);
      hv[j] = __half2float(h[(long)sj * D1 + lane]);
    }
#pragma unroll
    for (int j = 0; j < 8; ++j) {
      float a = __shfl(al, j * 8 + myh, 64);
      acc = fmaf(hv[j], a, acc);
    }
  }
  if (i < end) {
    float mmy = __shfl(m, myh, 64);
    float imy = __shfl(invd, myh, 64);
    float amy = ad[node * H1 + myh];
    for (; i < end; ++i) {
      int s = csr[i];
      float v = as[s * H1 + myh] + amy;
      v = v >= 0.f ? v : NEG * v;
      float a = __expf(v - mmy) * imy;
      acc = fmaf(__half2float(h[(long)s * D1 + lane]), a, acc);
    }
  }
  float o = acc + b1[lane];
  emb[(long)node * D1 + lane] = o > 0.f ? o : expm1f(o);
}

// ---------- layer 2: h2 = emb @ W2 (fp16 out) ----------
__global__ __launch_bounds__(256) void gemm2_kernel(
    const float* __restrict__ emb, const float* __restrict__ W2, __half* __restrict__ h2) {
  __shared__ float sW[D1 * C2];  // 10 KB
  int t = threadIdx.x;
  for (int i = t; i < D1 * C2; i += 256) sW[i] = W2[i];
  __syncthreads();
  int gid = blockIdx.x * 256 + t;
  if (gid >= NN * C2) return;
  int n = gid / C2, c = gid % C2;
  float accv = 0.f;
  const float* er = &emb[(long)n * D1];
#pragma unroll 8
  for (int k = 0; k < D1; ++k) accv = fmaf(er[k], sW[k * C2 + c], accv);
  h2[gid] = __float2half(accv);
}

__global__ void attdot2_kernel(const __half* __restrict__ h2, const float* __restrict__ att_s,
                               const float* __restrict__ att_d,
                               float* __restrict__ as, float* __restrict__ ad) {
  int n = blockIdx.x * blockDim.x + threadIdx.x;
  if (n >= NN) return;
  float vs = 0.f, vd = 0.f;
  const __half* r = &h2[(long)n * C2];
#pragma unroll
  for (int c = 0; c < C2; ++c) {
    float v = __half2float(r[c]);
    vs = fmaf(v, att_s[c], vs);
    vd = fmaf(v, att_d[c], vd);
  }
  as[n] = vs;
  ad[n] = vd;
}

// ---------- fused aggregation, layer 2 + bias + log_softmax ----------
__global__ __launch_bounds__(256) void agg2_kernel(
    const int* __restrict__ rowptr, const int* __restrict__ csr,
    const float* __restrict__ as, const float* __restrict__ ad,
    const __half* __restrict__ h2, const float* __restrict__ b2,
    float* __restrict__ out) {
  int node = blockIdx.x * 4 + (threadIdx.x >> 6);
  if (node >= NN) return;
  int lane = threadIdx.x & 63;
  int beg = rowptr[node];
  int end = (node == NN - 1) ? ET : rowptr[node + 1];
  float adv = ad[node];

  // phase 1: max and denom
  float m = -INFINITY;
  for (int i = beg + lane; i < end; i += 64) {
    float v = as[csr[i]] + adv;
    v = v >= 0.f ? v : NEG * v;
    m = fmaxf(m, v);
  }
#pragma unroll
  for (int off = 1; off < 64; off <<= 1) m = fmaxf(m, __shfl_xor(m, off, 64));
  float den = 0.f;
  for (int i = beg + lane; i < end; i += 64) {
    float v = as[csr[i]] + adv;
    v = v >= 0.f ? v : NEG * v;
    den += __expf(v - m);
  }
#pragma unroll
  for (int off = 1; off < 64; off <<= 1) den += __shfl_xor(den, off, 64);
  float invd = 1.f / (den + EPSV);

  // phase 2: chunked gather, 64 edges at a time; each lane computes one alpha
  float acc = 0.f;
  for (int base = beg; base < end; base += 64) {
    int nch = min(64, end - base);
    int s_m = 0;
    float al = 0.f;
    if (lane < nch) {
      s_m = csr[base + lane];
      float v = as[s_m] + adv;
      v = v >= 0.f ? v : NEG * v;
      al = __expf(v - m) * invd;
    }
    for (int j = 0; j < nch; ++j) {
      int s = __shfl(s_m, j, 64);
      float a = __shfl(al, j, 64);
      if (lane < C2) acc = fmaf(__half2float(h2[(long)s * C2 + lane]), a, acc);
    }
  }

  // fused bias + log_softmax
  float val = (lane < C2) ? acc + b2[lane] : -INFINITY;
  float m2 = val;
#pragma unroll
  for (int off = 1; off < 64; off <<= 1) m2 = fmaxf(m2, __shfl_xor(m2, off, 64));
  float ex = (lane < C2) ? __expf(val - m2) : 0.f;
  float sum = ex;
#pragma unroll
  for (int off = 1; off < 64; off <<= 1) sum += __shfl_xor(sum, off, 64);
  if (lane < C2) out[(long)node * C2 + lane] = val - m2 - logf(sum);
}

// ---------- launch ----------
extern "C" void kernel_launch(void* const* d_in, const int* in_sizes, int n_in,
                              void* d_out, int out_size, void* d_ws, size_t ws_size,
                              hipStream_t stream) {
  const float* x    = (const float*)d_in[0];
  const float* W1   = (const float*)d_in[1];
  const float* as1w = (const float*)d_in[2];
  const float* ad1w = (const float*)d_in[3];
  const float* b1   = (const float*)d_in[4];
  const float* W2   = (const float*)d_in[5];
  const float* as2w = (const float*)d_in[6];
  const float* ad2w = (const float*)d_in[7];
  const float* b2   = (const float*)d_in[8];
  const int*   ei   = (const int*)d_in[9];

  float* out   = (float*)d_out;
  float* outls = out;                    // [N,40] log_softmax
  float* emb   = out + (long)NN * C2;    // [N,64] emb

  char* wsb = (char*)d_ws;
  __half* h1   = (__half*)wsb; wsb += sizeof(__half) * (size_t)NN * D1;
  __half* h2   = (__half*)wsb; wsb += sizeof(__half) * (size_t)NN * C2;
  float* asrc1 = (float*)wsb; wsb += sizeof(float) * (size_t)NN * H1;
  float* adst1 = (float*)wsb; wsb += sizeof(float) * (size_t)NN * H1;
  float* asrc2 = (float*)wsb; wsb += sizeof(float) * (size_t)NN;
  float* adst2 = (float*)wsb; wsb += sizeof(float) * (size_t)NN;
  int* deg     = (int*)wsb;   wsb += sizeof(int) * (size_t)NN;
  int* rowptr  = (int*)wsb;   wsb += sizeof(int) * (size_t)NN;
  int* cursor  = (int*)wsb;   wsb += sizeof(int) * (size_t)NN;
  int* partial = (int*)wsb;   wsb += sizeof(int) * 256;
  int* csr     = (int*)wsb;   wsb += sizeof(int) * (size_t)ET;

  // CSR build (per call; ws is re-poisoned each launch)
  hipMemsetAsync(deg, 0, sizeof(int) * (size_t)NN, stream);
  hipMemsetAsync(cursor, 0, sizeof(int) * (size_t)NN, stream);
  int nbE = (ET + 255) / 256;
  deg_kernel<<<nbE, 256, 0, stream>>>(ei, deg);
  scan1_kernel<<<NB_SCAN, 256, 0, stream>>>(deg, rowptr, partial);
  scan2_kernel<<<1, 64, 0, stream>>>(partial);
  scan3_kernel<<<(NN + 255) / 256, 256, 0, stream>>>(rowptr, partial);
  fill_csr_kernel<<<nbE, 256, 0, stream>>>(ei, rowptr, cursor, csr);

  // layer 1
  gemm1_kernel<<<(NN + 3) / 4, 256, 0, stream>>>(x, W1, as1w, ad1w, h1, asrc1, adst1);
  agg1_kernel<<<(NN + 3) / 4, 256, 0, stream>>>(rowptr, csr, asrc1, adst1, h1, b1, emb);

  // layer 2
  gemm2_kernel<<<(NN * C2 + 255) / 256, 256, 0, stream>>>(emb, W2, h2);
  attdot2_kernel<<<(NN + 255) / 256, 256, 0, stream>>>(h2, as2w, ad2w, asrc2, adst2);
  agg2_kernel<<<(NN + 3) / 4, 256, 0, stream>>>(rowptr, csr, asrc2, adst2, h2, b2, outls);
}

// Round 4
// 656.844 us; speedup vs baseline: 7.6184x; 1.0260x over previous
//
#include <hip/hip_runtime.h>
#include <hip/hip_fp16.h>
#include <math.h>

#define NN 100000
#define EE 1600000
#define ET (EE + NN)   // 1,700,000 edges incl self-loops
#define FIN 128
#define D1 64          // H1*C1
#define H1 8
#define C1 8
#define C2 40
#define NEG 0.2f
#define EPSV 1e-16f

__device__ __forceinline__ void edge_sd(int e, const int* __restrict__ ei, int& s, int& d) {
  if (e < EE) { s = ei[e]; d = ei[EE + e]; }
  else        { s = e - EE; d = s; }
}

// ---------- CSR build ----------
__global__ void deg_kernel(const int* __restrict__ ei, int* __restrict__ deg) {
  int e = blockIdx.x * 256 + threadIdx.x;
  if (e >= ET) return;
  int s, d; edge_sd(e, ei, s, d);
  atomicAdd(&deg[d], 1);
}

#define NB_SCAN ((NN + 1023) / 1024)
__global__ __launch_bounds__(256) void scan1_kernel(const int* __restrict__ deg,
                                                    int* __restrict__ rowptr,
                                                    int* __restrict__ partial) {
  __shared__ int sd[256];
  int b = blockIdx.x, t = threadIdx.x;
  int base = b * 1024 + t * 4;
  int v[4], s = 0;
#pragma unroll
  for (int j = 0; j < 4; ++j) { int idx = base + j; v[j] = (idx < NN) ? deg[idx] : 0; s += v[j]; }
  sd[t] = s;
  __syncthreads();
  for (int off = 1; off < 256; off <<= 1) {
    int x = sd[t];
    int y = (t >= off) ? sd[t - off] : 0;
    __syncthreads();
    sd[t] = x + y;
    __syncthreads();
  }
  int run = sd[t] - s;
#pragma unroll
  for (int j = 0; j < 4; ++j) {
    int idx = base + j;
    if (idx < NN) rowptr[idx] = run;
    run += v[j];
  }
  if (t == 255) partial[b] = sd[255];
}

__global__ void scan2_kernel(int* __restrict__ partial) {
  if (threadIdx.x == 0 && blockIdx.x == 0) {
    int run = 0;
    for (int i = 0; i < NB_SCAN; ++i) { int p = partial[i]; partial[i] = run; run += p; }
  }
}

__global__ void scan3_kernel(int* __restrict__ rowptr, const int* __restrict__ partial) {
  int idx = blockIdx.x * 256 + threadIdx.x;
  if (idx < NN) rowptr[idx] += partial[idx >> 10];
}

__global__ void fill_csr_kernel(const int* __restrict__ ei, const int* __restrict__ rowptr,
                                int* __restrict__ cursor, int* __restrict__ csr) {
  int e = blockIdx.x * 256 + threadIdx.x;
  if (e >= ET) return;
  int s, d; edge_sd(e, ei, s, d);
  int pos = atomicAdd(&cursor[d], 1);
  csr[rowptr[d] + pos] = s;
}

// ---------- layer 1: h1 = x @ W1 (fp16 out) + per-head attention dots ----------
__global__ __launch_bounds__(256) void gemm1_kernel(
    const float* __restrict__ x, const float* __restrict__ W,
    const float* __restrict__ att_s, const float* __restrict__ att_d,
    __half* __restrict__ h, float* __restrict__ as, float* __restrict__ ad) {
  __shared__ float sW[FIN * D1];   // 32 KB
  __shared__ float sx[4 * FIN];    // 2 KB
  int t = threadIdx.x;
  for (int i = t; i < FIN * D1; i += 256) sW[i] = W[i];
  int node0 = blockIdx.x * 4;
  for (int i = t; i < 4 * FIN; i += 256) {
    int n = node0 + (i >> 7);
    sx[i] = (n < NN) ? x[(long)n * FIN + (i & 127)] : 0.f;
  }
  __syncthreads();
  int ln = t >> 6, col = t & 63;
  int n = node0 + ln;
  float acc = 0.f;
  const float* xr = &sx[ln * FIN];
#pragma unroll 8
  for (int k = 0; k < FIN; ++k) acc = fmaf(xr[k], sW[k * D1 + col], acc);
  float vs = acc * att_s[col];
  float vd = acc * att_d[col];
#pragma unroll
  for (int off = 1; off < 8; off <<= 1) {
    vs += __shfl_xor(vs, off, 64);
    vd += __shfl_xor(vd, off, 64);
  }
  if (n < NN) {
    h[(long)n * D1 + col] = __float2half(acc);
    if ((col & 7) == 0) {
      as[n * H1 + (col >> 3)] = vs;
      ad[n * H1 + (col >> 3)] = vd;
    }
  }
}

// ---------- fused aggregation, layer 1: single pass, no max-shift ----------
// one wave per dst node; lane = output column, head = lane>>3.
// out = (sum_j e_j * h_j) / (sum_j e_j + eps); src ids broadcast via readlane.
__global__ __launch_bounds__(256) void agg1_kernel(
    const int* __restrict__ rowptr, const int* __restrict__ csr,
    const float* __restrict__ as, const float* __restrict__ ad,
    const __half* __restrict__ h, const float* __restrict__ b1,
    float* __restrict__ emb) {
  int node = blockIdx.x * 4 + (threadIdx.x >> 6);
  if (node >= NN) return;
  int lane = threadIdx.x & 63;
  int myh = lane >> 3;
  int beg = rowptr[node];
  int end = (node == NN - 1) ? ET : rowptr[node + 1];
  float adv = ad[node * H1 + myh];
  float den = 0.f, acc = 0.f;
  for (int i = beg; i < end; i += 64) {
    int nch = min(64, end - i);
    int s64 = csr[i + min(lane, nch - 1)];
#pragma unroll 4
    for (int j = 0; j < nch; ++j) {
      int sj = __builtin_amdgcn_readlane(s64, j);  // wave-uniform src id (SGPR)
      float v = as[sj * H1 + myh] + adv;
      v = v >= 0.f ? v : NEG * v;
      float e = __expf(v);
      den += e;
      acc = fmaf(__half2float(h[(long)sj * D1 + lane]), e, acc);
    }
  }
  float o = acc / (den + EPSV) + b1[lane];
  emb[(long)node * D1 + lane] = o > 0.f ? o : expm1f(o);
}

// ---------- layer 2: h2 = emb @ W2 (fp16 out) ----------
__global__ __launch_bounds__(256) void gemm2_kernel(
    const float* __restrict__ emb, const float* __restrict__ W2, __half* __restrict__ h2) {
  __shared__ float sW[D1 * C2];  // 10 KB
  int t = threadIdx.x;
  for (int i = t; i < D1 * C2; i += 256) sW[i] = W2[i];
  __syncthreads();
  int gid = blockIdx.x * 256 + t;
  if (gid >= NN * C2) return;
  int n = gid / C2, c = gid % C2;
  float accv = 0.f;
  const float* er = &emb[(long)n * D1];
#pragma unroll 8
  for (int k = 0; k < D1; ++k) accv = fmaf(er[k], sW[k * C2 + c], accv);
  h2[gid] = __float2half(accv);
}

__global__ void attdot2_kernel(const __half* __restrict__ h2, const float* __restrict__ att_s,
                               const float* __restrict__ att_d,
                               float* __restrict__ as, float* __restrict__ ad) {
  int n = blockIdx.x * blockDim.x + threadIdx.x;
  if (n >= NN) return;
  float vs = 0.f, vd = 0.f;
  const __half* r = &h2[(long)n * C2];
#pragma unroll
  for (int c = 0; c < C2; ++c) {
    float v = __half2float(r[c]);
    vs = fmaf(v, att_s[c], vs);
    vd = fmaf(v, att_d[c], vd);
  }
  as[n] = vs;
  ad[n] = vd;
}

// ---------- fused aggregation, layer 2 + bias + log_softmax: single pass ----------
// lanes 0..39 = class columns; lanes 40..63 load h2 pad garbage (finite),
// excluded by the -INF mask in the softmax epilogue. h2 padded by 64 elems.
__global__ __launch_bounds__(256) void agg2_kernel(
    const int* __restrict__ rowptr, const int* __restrict__ csr,
    const float* __restrict__ as, const float* __restrict__ ad,
    const __half* __restrict__ h2, const float* __restrict__ b2,
    float* __restrict__ out) {
  int node = blockIdx.x * 4 + (threadIdx.x >> 6);
  if (node >= NN) return;
  int lane = threadIdx.x & 63;
  int beg = rowptr[node];
  int end = (node == NN - 1) ? ET : rowptr[node + 1];
  float adv = ad[node];
  float den = 0.f, acc = 0.f;
  for (int i = beg; i < end; i += 64) {
    int nch = min(64, end - i);
    int s64 = csr[i + min(lane, nch - 1)];
#pragma unroll 4
    for (int j = 0; j < nch; ++j) {
      int sj = __builtin_amdgcn_readlane(s64, j);  // wave-uniform src id
      float v = as[sj] + adv;                      // scalar/broadcast load
      v = v >= 0.f ? v : NEG * v;
      float e = __expf(v);
      den += e;
      acc = fmaf(__half2float(h2[(long)sj * C2 + lane]), e, acc);
    }
  }
  // bias + log_softmax over 40 classes
  float val = (lane < C2) ? acc / (den + EPSV) + b2[lane] : -INFINITY;
  float m2 = val;
#pragma unroll
  for (int off = 1; off < 64; off <<= 1) m2 = fmaxf(m2, __shfl_xor(m2, off, 64));
  float ex = (lane < C2) ? __expf(val - m2) : 0.f;
  float sum = ex;
#pragma unroll
  for (int off = 1; off < 64; off <<= 1) sum += __shfl_xor(sum, off, 64);
  if (lane < C2) out[(long)node * C2 + lane] = val - m2 - logf(sum);
}

// ---------- launch ----------
extern "C" void kernel_launch(void* const* d_in, const int* in_sizes, int n_in,
                              void* d_out, int out_size, void* d_ws, size_t ws_size,
                              hipStream_t stream) {
  const float* x    = (const float*)d_in[0];
  const float* W1   = (const float*)d_in[1];
  const float* as1w = (const float*)d_in[2];
  const float* ad1w = (const float*)d_in[3];
  const float* b1   = (const float*)d_in[4];
  const float* W2   = (const float*)d_in[5];
  const float* as2w = (const float*)d_in[6];
  const float* ad2w = (const float*)d_in[7];
  const float* b2   = (const float*)d_in[8];
  const int*   ei   = (const int*)d_in[9];

  float* out   = (float*)d_out;
  float* outls = out;                    // [N,40] log_softmax
  float* emb   = out + (long)NN * C2;    // [N,64] emb

  char* wsb = (char*)d_ws;
  __half* h1   = (__half*)wsb; wsb += sizeof(__half) * (size_t)NN * D1;
  __half* h2   = (__half*)wsb; wsb += sizeof(__half) * ((size_t)NN * C2 + 64);  // +64 pad
  float* asrc1 = (float*)wsb; wsb += sizeof(float) * (size_t)NN * H1;
  float* adst1 = (float*)wsb; wsb += sizeof(float) * (size_t)NN * H1;
  float* asrc2 = (float*)wsb; wsb += sizeof(float) * (size_t)NN;
  float* adst2 = (float*)wsb; wsb += sizeof(float) * (size_t)NN;
  int* deg     = (int*)wsb;   wsb += sizeof(int) * (size_t)NN;
  int* rowptr  = (int*)wsb;   wsb += sizeof(int) * (size_t)NN;
  int* cursor  = (int*)wsb;   wsb += sizeof(int) * (size_t)NN;
  int* partial = (int*)wsb;   wsb += sizeof(int) * 256;
  int* csr     = (int*)wsb;   wsb += sizeof(int) * (size_t)ET;

  // CSR build (per call; ws is re-poisoned each launch)
  hipMemsetAsync(deg, 0, sizeof(int) * (size_t)NN, stream);
  hipMemsetAsync(cursor, 0, sizeof(int) * (size_t)NN, stream);
  int nbE = (ET + 255) / 256;
  deg_kernel<<<nbE, 256, 0, stream>>>(ei, deg);
  scan1_kernel<<<NB_SCAN, 256, 0, stream>>>(deg, rowptr, partial);
  scan2_kernel<<<1, 64, 0, stream>>>(partial);
  scan3_kernel<<<(NN + 255) / 256, 256, 0, stream>>>(rowptr, partial);
  fill_csr_kernel<<<nbE, 256, 0, stream>>>(ei, rowptr, cursor, csr);

  // layer 1
  gemm1_kernel<<<(NN + 3) / 4, 256, 0, stream>>>(x, W1, as1w, ad1w, h1, asrc1, adst1);
  agg1_kernel<<<(NN + 3) / 4, 256, 0, stream>>>(rowptr, csr, asrc1, adst1, h1, b1, emb);

  // layer 2
  gemm2_kernel<<<(NN * C2 + 255) / 256, 256, 0, stream>>>(emb, W2, h2);
  attdot2_kernel<<<(NN + 255) / 256, 256, 0, stream>>>(h2, as2w, ad2w, asrc2, adst2);
  agg2_kernel<<<(NN + 3) / 4, 256, 0, stream>>>(rowptr, csr, asrc2, adst2, h2, b2, outls);
}